// Round 17
// baseline (495.783 us; speedup 1.0000x reference)
//
#include <hip/hip_runtime.h>
#include <hip/hip_bf16.h>

typedef __bf16 bf16_t;
typedef __bf16 bf16x8 __attribute__((ext_vector_type(8)));
typedef float f32x4 __attribute__((ext_vector_type(4)));

#define B_ 8
#define LQ_ 2048
#define LK_ 2048
#define DM_ 1024

__device__ __forceinline__ void gload16(const void* g, void* l) {
  __builtin_amdgcn_global_load_lds(
      (const __attribute__((address_space(1))) void*)g,
      (__attribute__((address_space(3))) void*)l, 16, 0, 0);
}

// ------------- fused prep: x/keys/Wq f32->bf16 + V transpose -------------
__global__ __launch_bounds__(256) void prep_kernel(
    const float* __restrict__ x, const float* __restrict__ keys,
    const float* __restrict__ Wq, const float* __restrict__ vals,
    bf16_t* __restrict__ xbf, bf16_t* __restrict__ kbf,
    bf16_t* __restrict__ wqbf, bf16_t* __restrict__ vt) {
  const int bid = blockIdx.x;
  const int tid = threadIdx.x;
  if (bid < 2176) {
    const float* in;
    bf16_t* out;
    int n8, i0, nb;
    if (bid < 1024) {
      in = x; out = xbf; n8 = (B_ * LQ_ * DM_) / 8; i0 = bid; nb = 1024;
    } else if (bid < 2048) {
      in = keys; out = kbf; n8 = (B_ * LK_ * DM_) / 8; i0 = bid - 1024; nb = 1024;
    } else {
      in = Wq; out = wqbf; n8 = (DM_ * DM_) / 8; i0 = bid - 2048; nb = 128;
    }
    int stride = nb * 256;
    for (int i = i0 * 256 + tid; i < n8; i += stride) {
      const float4* p = reinterpret_cast<const float4*>(in) + (size_t)i * 2;
      float4 a = p[0], b = p[1];
      bf16x8 o;
      o[0] = (bf16_t)a.x; o[1] = (bf16_t)a.y; o[2] = (bf16_t)a.z; o[3] = (bf16_t)a.w;
      o[4] = (bf16_t)b.x; o[5] = (bf16_t)b.y; o[6] = (bf16_t)b.z; o[7] = (bf16_t)b.w;
      *reinterpret_cast<bf16x8*>(out + (size_t)i * 8) = o;
    }
  } else {
    __shared__ bf16_t tile[64][65];
    const int t = bid - 2176;            // 0..4095
    const int k0 = (t & 31) * 64;
    const int d0 = ((t >> 5) & 15) * 64;
    const int b = t >> 9;
    const float* src = vals + ((size_t)b * LK_ + k0) * DM_ + d0;
    const int lr = tid >> 4;
    const int lc = (tid & 15) * 4;
#pragma unroll
    for (int rr = 0; rr < 64; rr += 16) {
      float4 v = *reinterpret_cast<const float4*>(src + (size_t)(rr + lr) * DM_ + lc);
      bf16_t* d = &tile[rr + lr][lc];
      d[0] = (bf16_t)v.x; d[1] = (bf16_t)v.y; d[2] = (bf16_t)v.z; d[3] = (bf16_t)v.w;
    }
    __syncthreads();
    bf16_t* dst = vt + ((size_t)b * DM_ + d0) * LK_ + k0;
    const int sd = tid >> 3;
    const int sk = (tid & 7) * 8;
#pragma unroll
    for (int pass = 0; pass < 2; ++pass) {
      const int d = pass * 32 + sd;
      bf16x8 o;
#pragma unroll
      for (int j = 0; j < 8; ++j) o[j] = tile[sk + j][d];
      *reinterpret_cast<bf16x8*>(dst + (size_t)d * LK_ + sk) = o;
    }
  }
}

// ---------------- 256x256 8-phase GEMM, C = A * B^T (r8 skeleton) ---------
// Race-free skeleton: every vmcnt drain sits BEFORE the end-of-phase
// barrier; staged regions are read only in phases after that drain+barrier.
// BK=64, 2 K-tiles/iter, 8 waves (2Mx4N), wave tile 128x64, 128 KiB LDS.
// K-slot swizzle (involution): phys_slot = slot ^ ((row>>1)&7), 8x16B slots.
// launch_bounds(512,1): LDS already caps occupancy at 1 block/CU (8 waves),
// so the 256-reg cap costs nothing and gives MODE 2's rs[8] headroom
// (r7's spill was the (512,2) 128-reg cap).
// MODE 0: C bf16, C += bias[col]                    (Q projection)
// MODE 1: C bf16, C = exp(C/32 + mask[b][col])      (unnormalized P)
// MODE 2: C f32,  C = (P@V^T)/rowsum(P); rowsums accumulated in-loop from
//         the A-fragments (each PV block reads its rows' FULL P row, K=LK)
#define BARX __builtin_amdgcn_s_barrier()
#define PRIO1 __builtin_amdgcn_s_setprio(1)
#define PRIO0 __builtin_amdgcn_s_setprio(0)
#define AS_F(u) __uint_as_float(u)

#define RD_A(QM, DOFF)                                                        \
  _Pragma("unroll") for (int m = 0; m < 4; ++m) {                             \
    aF[m][0] = *(const bf16x8*)(pa0 + (QM)*8192 + (DOFF) + m * 2048);         \
    aF[m][1] = *(const bf16x8*)(pa1 + (QM)*8192 + (DOFF) + m * 2048);         \
  }
#define RD_B2(NB, DOFF)                                                       \
  _Pragma("unroll") for (int n = 0; n < 2; ++n) {                             \
    bF[(NB) + n][0] = *(const bf16x8*)(pb0 + (DOFF) + ((NB) + n) * 2048);     \
    bF[(NB) + n][1] = *(const bf16x8*)(pb1 + (DOFF) + ((NB) + n) * 2048);     \
  }
#define MFMA_QUAD(MB, NB)                                                     \
  _Pragma("unroll") for (int m = 0; m < 4; ++m)                               \
  _Pragma("unroll") for (int n = 0; n < 2; ++n)                               \
    acc[(MB) + m][(NB) + n] = __builtin_amdgcn_mfma_f32_16x16x32_bf16(        \
        aF[m][0], bF[(NB) + n][0], acc[(MB) + m][(NB) + n], 0, 0, 0);         \
  _Pragma("unroll") for (int m = 0; m < 4; ++m)                               \
  _Pragma("unroll") for (int n = 0; n < 2; ++n)                               \
    acc[(MB) + m][(NB) + n] = __builtin_amdgcn_mfma_f32_16x16x32_bf16(        \
        aF[m][1], bF[(NB) + n][1], acc[(MB) + m][(NB) + n], 0, 0, 0);
// sum the 8 bf16 of both kk-fragments of aF[m] into rs[QM*4+m] (MODE 2 only)
#define ACC_RS(QM)                                                            \
  _Pragma("unroll") for (int m = 0; m < 4; ++m)                               \
  _Pragma("unroll") for (int kk = 0; kk < 2; ++kk) {                          \
    uint4 u = *reinterpret_cast<const uint4*>(&aF[m][kk]);                    \
    rs[(QM)*4 + m] += AS_F(u.x << 16) + AS_F(u.x & 0xffff0000u) +             \
                      AS_F(u.y << 16) + AS_F(u.y & 0xffff0000u) +             \
                      AS_F(u.z << 16) + AS_F(u.z & 0xffff0000u) +             \
                      AS_F(u.w << 16) + AS_F(u.w & 0xffff0000u);              \
  }

template <int MODE>
__global__ __launch_bounds__(512, 1) void gemm_bt(
    const bf16_t* __restrict__ A, const bf16_t* __restrict__ Bm,
    void* __restrict__ Cv, const float* __restrict__ extra,
    int N, int K, long sA, long sB, long sC, long sE, int gxs, int gys) {
  __shared__ bf16_t lds[65536];  // A: d0 [0,32KB) d1 [32,64KB); B: [64,128KB)

  const int tid = threadIdx.x;
  const int lane = tid & 63;
  const int wave = tid >> 6;

  // XCD-aware bijective block swizzle (gridDim.x % 8 == 0 for all our grids)
  const int nwg = gridDim.x;
  const int lin = blockIdx.x;
  const int cpx = nwg >> 3;
  const int swz = (lin & 7) * cpx + (lin >> 3);
  const int gx = 1 << gxs;
  const int bx = swz & (gx - 1);
  const int rem = swz >> gxs;
  const int by = rem & ((1 << gys) - 1);
  const int bz = rem >> gys;

  const bf16_t* Ab = A + (long)bz * sA + (long)(by * 256) * K;
  const bf16_t* Bb = Bm + (long)bz * sB + (long)(bx * 256) * K;

  // staging geometry: chunk c = tid; row-in-half = c>>3, phys slot c&7
  const int r0 = tid >> 3;                              // 0..63
  const int scol = ((tid & 7) ^ ((r0 >> 1) & 7)) * 8;   // pre-swizzled col

  auto STG = [&](const bf16_t* Mb, int d, int mat, int h, int t) {
    const bf16_t* g = Mb + (long)(h * 128 + r0) * K + t * 64 + scol;
    bf16_t* l = lds + mat * 32768 + d * 16384 + h * 8192 + wave * 512;
    gload16(g, l);
    gload16(g + (long)64 * K, l + 4096);
  };

  // fragment read geometry
  const int wr = wave >> 2;   // 0..1
  const int wc = wave & 3;    // 0..3
  const int fr = lane & 15;
  const int g = lane >> 4;
  const int q5 = (fr >> 1) & 7;
  const int sb0 = (g ^ q5) * 16;         // kk=0 slot bytes (phys)
  const int sb1 = ((4 + g) ^ q5) * 16;   // kk=1
  const char* ldsc = (const char*)lds;
  const char* pa0 = ldsc + (wr * 128 + fr) * 128 + sb0;
  const char* pa1 = ldsc + (wr * 128 + fr) * 128 + sb1;
  const char* pb0 = ldsc + 65536 + (wc * 64 + fr) * 128 + sb0;
  const char* pb1 = ldsc + 65536 + (wc * 64 + fr) * 128 + sb1;

  f32x4 acc[8][4] = {};
  bf16x8 aF[4][2], bF[4][2];
  float rs[8] = {0.f, 0.f, 0.f, 0.f, 0.f, 0.f, 0.f, 0.f};  // MODE 2 rowsums

  const int NT2 = K >> 7;  // iterations, 2 K-tiles (BK=64) each

  // prologue: t0 full (8 loads) + t1 B h0,h1 (4 loads)
  STG(Ab, 0, 0, 0, 0); STG(Ab, 0, 0, 1, 0);
  STG(Bb, 0, 1, 0, 0); STG(Bb, 0, 1, 1, 0);
  STG(Bb, 1, 1, 0, 1); STG(Bb, 1, 1, 1, 1);
  asm volatile("s_waitcnt vmcnt(4)" ::: "memory");  // t0 complete
  BARX;

  for (int j = 0; j < NT2; ++j) {
    const bool nl = (j + 1 < NT2);
    const int t1 = 2 * j + 1, t2 = 2 * j + 2, t3 = 2 * j + 3;
    // ---- P1: quadrant (qm0,qn01) of dbuf0 ----
    RD_A(0, 0); RD_B2(0, 0);
    STG(Ab, 1, 0, 0, t1);
    BARX; PRIO1; MFMA_QUAD(0, 0); PRIO0; BARX;
    // ---- P2: (qm0,qn23) ----
    RD_B2(2, 0);
    STG(Ab, 1, 0, 1, t1);
    if (MODE == 2) { ACC_RS(0); }
    BARX; PRIO1; MFMA_QUAD(0, 2); PRIO0; BARX;
    // ---- P3: (qm1,qn23) ----
    RD_A(1, 0);
    if (nl) STG(Bb, 0, 1, 0, t2);
    BARX; PRIO1; MFMA_QUAD(4, 2); PRIO0; BARX;
    // ---- P4: (qm1,qn01); dbuf1 must be complete after this phase ----
    if (nl) STG(Bb, 0, 1, 1, t2);
    if (MODE == 2) { ACC_RS(1); }
    BARX; PRIO1; MFMA_QUAD(4, 0); PRIO0;
    if (nl) { asm volatile("s_waitcnt vmcnt(4)" ::: "memory"); }
    else    { asm volatile("s_waitcnt vmcnt(0)" ::: "memory"); }
    BARX;
    // ---- P5: (qm0,qn01) of dbuf1 ----
    RD_A(0, 32768); RD_B2(0, 32768);
    if (nl) STG(Ab, 0, 0, 0, t2);
    BARX; PRIO1; MFMA_QUAD(0, 0); PRIO0; BARX;
    // ---- P6: (qm0,qn23) ----
    RD_B2(2, 32768);
    if (nl) STG(Ab, 0, 0, 1, t2);
    if (MODE == 2) { ACC_RS(0); }
    BARX; PRIO1; MFMA_QUAD(0, 2); PRIO0; BARX;
    // ---- P7: (qm1,qn23) ----
    RD_A(1, 32768);
    if (nl) STG(Bb, 1, 1, 0, t3);
    BARX; PRIO1; MFMA_QUAD(4, 2); PRIO0; BARX;
    // ---- P8: (qm1,qn01); dbuf0 must be complete after this phase ----
    if (nl) STG(Bb, 1, 1, 1, t3);
    if (MODE == 2) { ACC_RS(1); }
    BARX; PRIO1; MFMA_QUAD(4, 0); PRIO0;
    if (nl) { asm volatile("s_waitcnt vmcnt(4)" ::: "memory"); }
    BARX;
  }
  // loop exits with vmcnt==0 and all LDS reads complete -> LDS reusable.

  // epilogue
  const int cn = lane & 15;
  const int rr = (lane >> 4) * 4;
  const int row0 = by * 256 + wr * 128;
  const int col0 = bx * 256 + wc * 64;

  float* lds_rs = (float*)lds;
  if (MODE == 2) {
    // complete rowsums: reduce over the 4 k-lane-groups, broadcast via LDS.
#pragma unroll
    for (int i = 0; i < 8; ++i) {
      rs[i] += __shfl_xor(rs[i], 16, 64);
      rs[i] += __shfl_xor(rs[i], 32, 64);
    }
    if (wc == 0 && g == 0) {
#pragma unroll
      for (int m = 0; m < 8; ++m) lds_rs[wr * 128 + m * 16 + fr] = rs[m];
    }
    __syncthreads();
  }

#pragma unroll
  for (int m = 0; m < 8; ++m) {
    const int row = row0 + m * 16 + rr;
#pragma unroll
    for (int n = 0; n < 4; ++n) {
      const int col = col0 + n * 16 + cn;
      if (MODE == 0) {
        bf16_t* C = (bf16_t*)Cv;
        float bias = extra[col];
#pragma unroll
        for (int j = 0; j < 4; ++j)
          C[(long)(row + j) * N + col] = (bf16_t)(acc[m][n][j] + bias);
      } else if (MODE == 1) {
        bf16_t* C = (bf16_t*)Cv + (long)bz * sC;
        float mk = extra[(long)bz * sE + col];
#pragma unroll
        for (int j = 0; j < 4; ++j)
          C[(long)(row + j) * N + col] =
              (bf16_t)__expf(acc[m][n][j] * 0.03125f + mk);
      } else {
        float* C = (float*)Cv + (long)bz * sC;
#pragma unroll
        for (int j = 0; j < 4; ++j) {
          float inv = 1.0f / lds_rs[wr * 128 + m * 16 + rr + j];
          C[(long)(row + j) * N + col] = acc[m][n][j] * inv;
        }
      }
    }
  }
}

extern "C" void kernel_launch(void* const* d_in, const int* in_sizes, int n_in,
                              void* d_out, int out_size, void* d_ws, size_t ws_size,
                              hipStream_t stream) {
  const float* x    = (const float*)d_in[0];
  const float* mask = (const float*)d_in[1];
  const float* keys = (const float*)d_in[2];
  const float* vals = (const float*)d_in[3];
  const float* Wq   = (const float*)d_in[4];
  const float* bq   = (const float*)d_in[5];
  float* out = (float*)d_out;

  char* ws = (char*)d_ws;
  bf16_t* kbf    = (bf16_t*)(ws);
  bf16_t* vt     = (bf16_t*)(ws + 33554432);
  bf16_t* qbf    = (bf16_t*)(ws + 67108864);
  bf16_t* logits = (bf16_t*)(ws + 100663296);  // holds p_unnorm = exp(logit)
  bf16_t* xbf    = logits;  // reused: x_bf dead before logits are written
  bf16_t* wqbf   = (bf16_t*)(ws + 167772160);

  // 1. fused prep: converts + V transpose (one launch)
  prep_kernel<<<6272, 256, 0, stream>>>(x, keys, Wq, vals, xbf, kbf, wqbf, vt);

  // 2. Q = x @ Wq^T + bq   (M=16384, N=1024, K=1024) grid 4x64 = 256
  gemm_bt<0><<<256, 512, 0, stream>>>(
      xbf, wqbf, qbf, bq, DM_, DM_, 0, 0, 0, 0, 2, 6);

  // 3. p_unnorm = exp(Q @ K^T / 32 + mask)  (per batch M=2048,N=2048,K=1024)
  gemm_bt<1><<<512, 512, 0, stream>>>(
      qbf, kbf, logits, mask, LK_, DM_,
      (long)LQ_ * DM_, (long)LK_ * DM_, (long)LQ_ * LK_, LK_, 3, 3);

  // 4. out = (P @ Vt^T) / rowsum(P)  (per batch M=2048, N=1024, K=2048)
  gemm_bt<2><<<256, 512, 0, stream>>>(
      logits, vt, out, nullptr, DM_, LK_,
      (long)LQ_ * LK_, (long)DM_ * LK_, (long)LQ_ * DM_, 0, 2, 3);
}

// Round 18
// 231.680 us; speedup vs baseline: 2.1399x; 2.1399x over previous
//
#include <hip/hip_runtime.h>
#include <hip/hip_bf16.h>

typedef __bf16 bf16_t;
typedef __bf16 bf16x8 __attribute__((ext_vector_type(8)));
typedef float f32x4 __attribute__((ext_vector_type(4)));

#define B_ 8
#define LQ_ 2048
#define LK_ 2048
#define DM_ 1024

__device__ __forceinline__ void gload16(const void* g, void* l) {
  __builtin_amdgcn_global_load_lds(
      (const __attribute__((address_space(1))) void*)g,
      (__attribute__((address_space(3))) void*)l, 16, 0, 0);
}

// ------------- fused prep: x/keys/Wq f32->bf16 + V transpose -------------
__global__ __launch_bounds__(256) void prep_kernel(
    const float* __restrict__ x, const float* __restrict__ keys,
    const float* __restrict__ Wq, const float* __restrict__ vals,
    bf16_t* __restrict__ xbf, bf16_t* __restrict__ kbf,
    bf16_t* __restrict__ wqbf, bf16_t* __restrict__ vt) {
  const int bid = blockIdx.x;
  const int tid = threadIdx.x;
  if (bid < 2176) {
    const float* in;
    bf16_t* out;
    int n8, i0, nb;
    if (bid < 1024) {
      in = x; out = xbf; n8 = (B_ * LQ_ * DM_) / 8; i0 = bid; nb = 1024;
    } else if (bid < 2048) {
      in = keys; out = kbf; n8 = (B_ * LK_ * DM_) / 8; i0 = bid - 1024; nb = 1024;
    } else {
      in = Wq; out = wqbf; n8 = (DM_ * DM_) / 8; i0 = bid - 2048; nb = 128;
    }
    int stride = nb * 256;
    for (int i = i0 * 256 + tid; i < n8; i += stride) {
      const float4* p = reinterpret_cast<const float4*>(in) + (size_t)i * 2;
      float4 a = p[0], b = p[1];
      bf16x8 o;
      o[0] = (bf16_t)a.x; o[1] = (bf16_t)a.y; o[2] = (bf16_t)a.z; o[3] = (bf16_t)a.w;
      o[4] = (bf16_t)b.x; o[5] = (bf16_t)b.y; o[6] = (bf16_t)b.z; o[7] = (bf16_t)b.w;
      *reinterpret_cast<bf16x8*>(out + (size_t)i * 8) = o;
    }
  } else {
    __shared__ bf16_t tile[64][65];
    const int t = bid - 2176;            // 0..4095
    const int k0 = (t & 31) * 64;
    const int d0 = ((t >> 5) & 15) * 64;
    const int b = t >> 9;
    const float* src = vals + ((size_t)b * LK_ + k0) * DM_ + d0;
    const int lr = tid >> 4;
    const int lc = (tid & 15) * 4;
#pragma unroll
    for (int rr = 0; rr < 64; rr += 16) {
      float4 v = *reinterpret_cast<const float4*>(src + (size_t)(rr + lr) * DM_ + lc);
      bf16_t* d = &tile[rr + lr][lc];
      d[0] = (bf16_t)v.x; d[1] = (bf16_t)v.y; d[2] = (bf16_t)v.z; d[3] = (bf16_t)v.w;
    }
    __syncthreads();
    bf16_t* dst = vt + ((size_t)b * DM_ + d0) * LK_ + k0;
    const int sd = tid >> 3;
    const int sk = (tid & 7) * 8;
#pragma unroll
    for (int pass = 0; pass < 2; ++pass) {
      const int d = pass * 32 + sd;
      bf16x8 o;
#pragma unroll
      for (int j = 0; j < 8; ++j) o[j] = tile[sk + j][d];
      *reinterpret_cast<bf16x8*>(dst + (size_t)d * LK_ + sk) = o;
    }
  }
}

// ---------------- 256x256 8-phase GEMM, C = A * B^T (r8/r13 skeleton) -----
// Race-free skeleton: every vmcnt drain sits BEFORE the end-of-phase
// barrier; staged regions are read only in phases after that drain+barrier.
// BK=64, 2 K-tiles/iter, 8 waves (2Mx4N), wave tile 128x64, 128 KiB LDS.
// K-slot swizzle (involution): phys_slot = slot ^ ((row>>1)&7), 8x16B slots.
// REGISTER BUDGET (r7/r17 lesson): acc = 128 AGPRs; unified VGPR/AGPR file
// caps 256 total at 2 waves/SIMD (fixed by the 8-wave block shape), so
// NOTHING new may live across the K-loop in any MODE.
// MODE 0: C bf16, C += bias[col]                    (Q projection)
// MODE 1: C bf16, C = exp(C/32 + mask[b][col]); epilogue writes per-block
//         rowsum partials to extra2[bz][8][2048]
// MODE 2: C f32,  C = acc / rowsum; epilogue sums the 8 partials from
//         extra (=pbuf) for its 256 rows, inverts into LDS, multiplies.
#define BARX __builtin_amdgcn_s_barrier()
#define PRIO1 __builtin_amdgcn_s_setprio(1)
#define PRIO0 __builtin_amdgcn_s_setprio(0)

#define RD_A(QM, DOFF)                                                        \
  _Pragma("unroll") for (int m = 0; m < 4; ++m) {                             \
    aF[m][0] = *(const bf16x8*)(pa0 + (QM)*8192 + (DOFF) + m * 2048);         \
    aF[m][1] = *(const bf16x8*)(pa1 + (QM)*8192 + (DOFF) + m * 2048);         \
  }
#define RD_B2(NB, DOFF)                                                       \
  _Pragma("unroll") for (int n = 0; n < 2; ++n) {                             \
    bF[(NB) + n][0] = *(const bf16x8*)(pb0 + (DOFF) + ((NB) + n) * 2048);     \
    bF[(NB) + n][1] = *(const bf16x8*)(pb1 + (DOFF) + ((NB) + n) * 2048);     \
  }
#define MFMA_QUAD(MB, NB)                                                     \
  _Pragma("unroll") for (int m = 0; m < 4; ++m)                               \
  _Pragma("unroll") for (int n = 0; n < 2; ++n)                               \
    acc[(MB) + m][(NB) + n] = __builtin_amdgcn_mfma_f32_16x16x32_bf16(        \
        aF[m][0], bF[(NB) + n][0], acc[(MB) + m][(NB) + n], 0, 0, 0);         \
  _Pragma("unroll") for (int m = 0; m < 4; ++m)                               \
  _Pragma("unroll") for (int n = 0; n < 2; ++n)                               \
    acc[(MB) + m][(NB) + n] = __builtin_amdgcn_mfma_f32_16x16x32_bf16(        \
        aF[m][1], bF[(NB) + n][1], acc[(MB) + m][(NB) + n], 0, 0, 0);

template <int MODE>
__global__ __launch_bounds__(512, 2) void gemm_bt(
    const bf16_t* __restrict__ A, const bf16_t* __restrict__ Bm,
    void* __restrict__ Cv, const float* __restrict__ extra,
    float* __restrict__ extra2,
    int N, int K, long sA, long sB, long sC, long sE, int gxs, int gys) {
  __shared__ bf16_t lds[65536];  // A: d0 [0,32KB) d1 [32,64KB); B: [64,128KB)

  const int tid = threadIdx.x;
  const int lane = tid & 63;
  const int wave = tid >> 6;

  // XCD-aware bijective block swizzle (gridDim.x % 8 == 0 for all our grids)
  const int nwg = gridDim.x;
  const int lin = blockIdx.x;
  const int cpx = nwg >> 3;
  const int swz = (lin & 7) * cpx + (lin >> 3);
  const int gx = 1 << gxs;
  const int bx = swz & (gx - 1);
  const int rem = swz >> gxs;
  const int by = rem & ((1 << gys) - 1);
  const int bz = rem >> gys;

  const bf16_t* Ab = A + (long)bz * sA + (long)(by * 256) * K;
  const bf16_t* Bb = Bm + (long)bz * sB + (long)(bx * 256) * K;

  // staging geometry: chunk c = tid; row-in-half = c>>3, phys slot c&7
  const int r0 = tid >> 3;                              // 0..63
  const int scol = ((tid & 7) ^ ((r0 >> 1) & 7)) * 8;   // pre-swizzled col

  auto STG = [&](const bf16_t* Mb, int d, int mat, int h, int t) {
    const bf16_t* g = Mb + (long)(h * 128 + r0) * K + t * 64 + scol;
    bf16_t* l = lds + mat * 32768 + d * 16384 + h * 8192 + wave * 512;
    gload16(g, l);
    gload16(g + (long)64 * K, l + 4096);
  };

  // fragment read geometry
  const int wr = wave >> 2;   // 0..1
  const int wc = wave & 3;    // 0..3
  const int fr = lane & 15;
  const int g = lane >> 4;
  const int q5 = (fr >> 1) & 7;
  const int sb0 = (g ^ q5) * 16;         // kk=0 slot bytes (phys)
  const int sb1 = ((4 + g) ^ q5) * 16;   // kk=1
  const char* ldsc = (const char*)lds;
  const char* pa0 = ldsc + (wr * 128 + fr) * 128 + sb0;
  const char* pa1 = ldsc + (wr * 128 + fr) * 128 + sb1;
  const char* pb0 = ldsc + 65536 + (wc * 64 + fr) * 128 + sb0;
  const char* pb1 = ldsc + 65536 + (wc * 64 + fr) * 128 + sb1;

  f32x4 acc[8][4] = {};
  bf16x8 aF[4][2], bF[4][2];

  const int NT2 = K >> 7;  // iterations, 2 K-tiles (BK=64) each

  // prologue: t0 full (8 loads) + t1 B h0,h1 (4 loads)
  STG(Ab, 0, 0, 0, 0); STG(Ab, 0, 0, 1, 0);
  STG(Bb, 0, 1, 0, 0); STG(Bb, 0, 1, 1, 0);
  STG(Bb, 1, 1, 0, 1); STG(Bb, 1, 1, 1, 1);
  asm volatile("s_waitcnt vmcnt(4)" ::: "memory");  // t0 complete
  BARX;

  for (int j = 0; j < NT2; ++j) {
    const bool nl = (j + 1 < NT2);
    const int t1 = 2 * j + 1, t2 = 2 * j + 2, t3 = 2 * j + 3;
    // ---- P1: quadrant (qm0,qn01) of dbuf0 ----
    RD_A(0, 0); RD_B2(0, 0);
    STG(Ab, 1, 0, 0, t1);
    BARX; PRIO1; MFMA_QUAD(0, 0); PRIO0; BARX;
    // ---- P2: (qm0,qn23) ----
    RD_B2(2, 0);
    STG(Ab, 1, 0, 1, t1);
    BARX; PRIO1; MFMA_QUAD(0, 2); PRIO0; BARX;
    // ---- P3: (qm1,qn23) ----
    RD_A(1, 0);
    if (nl) STG(Bb, 0, 1, 0, t2);
    BARX; PRIO1; MFMA_QUAD(4, 2); PRIO0; BARX;
    // ---- P4: (qm1,qn01); dbuf1 must be complete after this phase ----
    if (nl) STG(Bb, 0, 1, 1, t2);
    BARX; PRIO1; MFMA_QUAD(4, 0); PRIO0;
    if (nl) { asm volatile("s_waitcnt vmcnt(4)" ::: "memory"); }
    else    { asm volatile("s_waitcnt vmcnt(0)" ::: "memory"); }
    BARX;
    // ---- P5: (qm0,qn01) of dbuf1 ----
    RD_A(0, 32768); RD_B2(0, 32768);
    if (nl) STG(Ab, 0, 0, 0, t2);
    BARX; PRIO1; MFMA_QUAD(0, 0); PRIO0; BARX;
    // ---- P6: (qm0,qn23) ----
    RD_B2(2, 32768);
    if (nl) STG(Ab, 0, 0, 1, t2);
    BARX; PRIO1; MFMA_QUAD(0, 2); PRIO0; BARX;
    // ---- P7: (qm1,qn23) ----
    RD_A(1, 32768);
    if (nl) STG(Bb, 1, 1, 0, t3);
    BARX; PRIO1; MFMA_QUAD(4, 2); PRIO0; BARX;
    // ---- P8: (qm1,qn01); dbuf0 must be complete after this phase ----
    if (nl) STG(Bb, 1, 1, 1, t3);
    BARX; PRIO1; MFMA_QUAD(4, 0); PRIO0;
    if (nl) { asm volatile("s_waitcnt vmcnt(4)" ::: "memory"); }
    BARX;
  }
  // loop exits with vmcnt==0 and all LDS reads complete -> LDS reusable.

  // epilogue
  const int cn = lane & 15;
  const int rr = (lane >> 4) * 4;
  const int row0 = by * 256 + wr * 128;
  const int col0 = bx * 256 + wc * 64;

  if (MODE == 0) {
    bf16_t* C = (bf16_t*)Cv;
#pragma unroll
    for (int m = 0; m < 8; ++m) {
      const int row = row0 + m * 16 + rr;
#pragma unroll
      for (int n = 0; n < 4; ++n) {
        const int col = col0 + n * 16 + cn;
        float bias = extra[col];
#pragma unroll
        for (int j = 0; j < 4; ++j)
          C[(long)(row + j) * N + col] = (bf16_t)(acc[m][n][j] + bias);
      }
    }
  } else if (MODE == 1) {
    bf16_t* C = (bf16_t*)Cv + (long)bz * sC;
    float* lds_f = (float*)lds;  // [wc][256 block-rows] wave-exclusive slots
#pragma unroll
    for (int m = 0; m < 8; ++m) {
      const int row = row0 + m * 16 + rr;
      float sm0 = 0.f, sm1 = 0.f, sm2 = 0.f, sm3 = 0.f;
#pragma unroll
      for (int n = 0; n < 4; ++n) {
        const int col = col0 + n * 16 + cn;
        float mk = extra[(long)bz * sE + col];
        float e0 = __expf(acc[m][n][0] * 0.03125f + mk);
        float e1 = __expf(acc[m][n][1] * 0.03125f + mk);
        float e2 = __expf(acc[m][n][2] * 0.03125f + mk);
        float e3 = __expf(acc[m][n][3] * 0.03125f + mk);
        C[(long)(row + 0) * N + col] = (bf16_t)e0;
        C[(long)(row + 1) * N + col] = (bf16_t)e1;
        C[(long)(row + 2) * N + col] = (bf16_t)e2;
        C[(long)(row + 3) * N + col] = (bf16_t)e3;
        sm0 += e0; sm1 += e1; sm2 += e2; sm3 += e3;
      }
      // column-reduce over the 16 lanes of this k-group (masks stay in-group)
#pragma unroll
      for (int w = 1; w < 16; w <<= 1) {
        sm0 += __shfl_xor(sm0, w, 64);
        sm1 += __shfl_xor(sm1, w, 64);
        sm2 += __shfl_xor(sm2, w, 64);
        sm3 += __shfl_xor(sm3, w, 64);
      }
      if (cn == 0) {
        const int br = wr * 128 + m * 16 + (lane >> 4) * 4;
        lds_f[wc * 256 + br + 0] = sm0;
        lds_f[wc * 256 + br + 1] = sm1;
        lds_f[wc * 256 + br + 2] = sm2;
        lds_f[wc * 256 + br + 3] = sm3;
      }
    }
    __syncthreads();
    if (tid < 256) {
      float s4 = lds_f[tid] + lds_f[256 + tid] + lds_f[512 + tid] +
                 lds_f[768 + tid];
      extra2[((long)bz * 8 + bx) * 2048 + by * 256 + tid] = s4;
    }
  } else {
    float* C = (float*)Cv + (long)bz * sC;
    // fused rowsum finalize: sum the 8 col-block partials for this block's
    // 256 rows, invert into LDS (free after the K-loop), then multiply.
    float* lds_rs = (float*)lds;
    if (tid < 256) {
      const float* pb = extra + (long)bz * 8 * 2048 + by * 256 + tid;
      float s = 0.f;
#pragma unroll
      for (int cb = 0; cb < 8; ++cb) s += pb[(long)cb * 2048];
      lds_rs[tid] = 1.0f / s;
    }
    __syncthreads();
#pragma unroll
    for (int m = 0; m < 8; ++m) {
      const int row = row0 + m * 16 + rr;
      const int rl = wr * 128 + m * 16 + rr;
      float i0 = lds_rs[rl + 0], i1 = lds_rs[rl + 1];
      float i2 = lds_rs[rl + 2], i3 = lds_rs[rl + 3];
#pragma unroll
      for (int n = 0; n < 4; ++n) {
        const int col = col0 + n * 16 + cn;
        C[(long)(row + 0) * N + col] = acc[m][n][0] * i0;
        C[(long)(row + 1) * N + col] = acc[m][n][1] * i1;
        C[(long)(row + 2) * N + col] = acc[m][n][2] * i2;
        C[(long)(row + 3) * N + col] = acc[m][n][3] * i3;
      }
    }
  }
}

extern "C" void kernel_launch(void* const* d_in, const int* in_sizes, int n_in,
                              void* d_out, int out_size, void* d_ws, size_t ws_size,
                              hipStream_t stream) {
  const float* x    = (const float*)d_in[0];
  const float* mask = (const float*)d_in[1];
  const float* keys = (const float*)d_in[2];
  const float* vals = (const float*)d_in[3];
  const float* Wq   = (const float*)d_in[4];
  const float* bq   = (const float*)d_in[5];
  float* out = (float*)d_out;

  char* ws = (char*)d_ws;
  bf16_t* kbf    = (bf16_t*)(ws);
  bf16_t* vt     = (bf16_t*)(ws + 33554432);
  bf16_t* qbf    = (bf16_t*)(ws + 67108864);
  bf16_t* logits = (bf16_t*)(ws + 100663296);  // holds p_unnorm = exp(logit)
  bf16_t* xbf    = logits;  // reused: x_bf dead before logits are written
  bf16_t* wqbf   = (bf16_t*)(ws + 167772160);
  // wqbf region (2 MB) is dead after Q-proj; reuse for rowsum partials:
  float* pbuf = (float*)(ws + 167772160);            // [8][8][2048]

  // 1. fused prep: converts + V transpose (one launch)
  prep_kernel<<<6272, 256, 0, stream>>>(x, keys, Wq, vals, xbf, kbf, wqbf, vt);

  // 2. Q = x @ Wq^T + bq   (M=16384, N=1024, K=1024) grid 4x64 = 256
  gemm_bt<0><<<256, 512, 0, stream>>>(
      xbf, wqbf, qbf, bq, nullptr, DM_, DM_, 0, 0, 0, 0, 2, 6);

  // 3. p_unnorm = exp(Q @ K^T / 32 + mask), + rowsum partials -> pbuf
  gemm_bt<1><<<512, 512, 0, stream>>>(
      qbf, kbf, logits, mask, pbuf, LK_, DM_,
      (long)LQ_ * DM_, (long)LK_ * DM_, (long)LQ_ * LK_, LK_, 3, 3);

  // 4. out = (P @ Vt^T) / rowsum(P)  (per batch M=2048, N=1024, K=2048),
  //    rowsum finalize fused into the epilogue (extra = pbuf)
  gemm_bt<2><<<256, 512, 0, stream>>>(
      logits, vt, out, pbuf, nullptr, DM_, LK_,
      (long)LQ_ * LK_, (long)DM_ * LK_, (long)LQ_ * DM_, 0, 2, 3);
}